// Round 1
// baseline (353.109 us; speedup 1.0000x reference)
//
#include <hip/hip_runtime.h>
#include <math.h>

#define NN 10000
#define BB 4
#define EE 160000
#define CC 64
#define CE 16

// ---- workspace layout (bytes) ----
static constexpr size_t OFF_XPA    = 0;          // float[NN*BB*CC]
static constexpr size_t OFF_XPB    = 10240000;   // float[NN*BB*CC]
static constexpr size_t OFF_SA     = 20480000;   // float[NN*BB]
static constexpr size_t OFF_SB     = 20640000;   // float[NN*BB]
static constexpr size_t OFF_VECS   = 20800000;   // float[288]
static constexpr size_t OFF_COUNTS = 20801280;   // int[NN]
static constexpr size_t OFF_CURSOR = 20841280;   // int[NN]
static constexpr size_t OFF_OFFS   = 20881280;   // int[NN+1]
static constexpr size_t OFF_RECS   = 20921344;   // int4[EE] {src, e, se1_bits, se2_bits} -> 23.5 MB total

__device__ __forceinline__ float sigmoidf_(float x) {
    // v_rcp_f32 approx (~1ulp) instead of IEEE divide: ~1 inst vs ~10
    return __builtin_amdgcn_rcpf(1.0f + __expf(-x));
}

// histogram of dst + (block 0) fold q@aw_q, k@aw_k, w_e@aw_e for both layers
__global__ void hist_vecs_kernel(const int* __restrict__ ei, int* __restrict__ counts,
                                 const float* __restrict__ q1, const float* __restrict__ k1,
                                 const float* __restrict__ aw1, const float* __restrict__ we1,
                                 const float* __restrict__ q2, const float* __restrict__ k2,
                                 const float* __restrict__ aw2, const float* __restrict__ we2,
                                 float* __restrict__ vecs) {
    int e = blockIdx.x * blockDim.x + threadIdx.x;
    if (e < EE) atomicAdd(&counts[ei[EE + e]], 1);
    if (blockIdx.x == 0) {
        int t = threadIdx.x;
        if (t < 64) {
            float a = 0.f, b = 0.f, c = 0.f, d = 0.f;
            for (int j = 0; j < 64; ++j) {
                a = fmaf(q1[t * 64 + j], aw1[j], a);
                b = fmaf(k1[t * 64 + j], aw1[64 + j], b);
                c = fmaf(q2[t * 64 + j], aw2[j], c);
                d = fmaf(k2[t * 64 + j], aw2[64 + j], d);
            }
            vecs[t] = a; vecs[64 + t] = b; vecs[144 + t] = c; vecs[208 + t] = d;
        }
        if (t < 16) {
            float a = 0.f, b = 0.f;
            for (int j = 0; j < 64; ++j) {
                a = fmaf(we1[t * 64 + j], aw1[128 + j], a);
                b = fmaf(we2[t * 64 + j], aw2[128 + j], b);
            }
            vecs[128 + t] = a; vecs[272 + t] = b;
        }
    }
}

// single-block exclusive scan of counts[0..n) -> offs[0..n].
// 10 elems/thread serial + shfl wave-scan + 16-partial combine: 1 barrier (was ~200).
__global__ __launch_bounds__(1024) void scan_kernel(const int* __restrict__ counts,
                                                    int* __restrict__ offs, int n) {
    __shared__ int wsum[16];
    int t = threadIdx.x;
    int base = t * 10;
    int v[10];
    int s = 0;
    #pragma unroll
    for (int j = 0; j < 10; ++j) {
        int i = base + j;
        v[j] = (i < n) ? counts[i] : 0;
        s += v[j];
    }
    int lane = t & 63, wid = t >> 6;
    int ps = s;
    #pragma unroll
    for (int off = 1; off < 64; off <<= 1) {
        int u = __shfl_up(ps, off, 64);
        if (lane >= off) ps += u;
    }
    if (lane == 63) wsum[wid] = ps;
    __syncthreads();
    int wbase = 0;
    for (int w = 0; w < wid; ++w) wbase += wsum[w];
    int tb = wbase + ps - s;  // exclusive prefix for this thread
    #pragma unroll
    for (int j = 0; j < 10; ++j) {
        int i = base + j;
        if (i < n) offs[i] = tb;
        tb += v[j];
    }
    if (t == 1023) offs[n] = tb;
}

// CSR scatter; also precompute per-edge scalar se = attr·(w_e@aw_e) + ab for both
// layers and embed it in the rec (removes att_kernel entirely).
__global__ __launch_bounds__(256) void scatter_kernel(
    const int* __restrict__ ei, const int* __restrict__ offs,
    int* __restrict__ cursor, const float* __restrict__ attr,
    const float* __restrict__ vecs, const float* __restrict__ ab1,
    const float* __restrict__ ab2, int4* __restrict__ recs) {
    int e = blockIdx.x * blockDim.x + threadIdx.x;
    if (e >= EE) return;
    int s = ei[e], d = ei[EE + e];
    const float4* ap = (const float4*)(attr + (size_t)e * CE);
    float4 a0 = ap[0], a1 = ap[1], a2 = ap[2], a3 = ap[3];
    const float* v1 = vecs + 128;
    const float* v2 = vecs + 272;
    float s1 = ab1[0], s2 = ab2[0];
    s1 = fmaf(a0.x, v1[0], s1);  s1 = fmaf(a0.y, v1[1], s1);
    s1 = fmaf(a0.z, v1[2], s1);  s1 = fmaf(a0.w, v1[3], s1);
    s1 = fmaf(a1.x, v1[4], s1);  s1 = fmaf(a1.y, v1[5], s1);
    s1 = fmaf(a1.z, v1[6], s1);  s1 = fmaf(a1.w, v1[7], s1);
    s1 = fmaf(a2.x, v1[8], s1);  s1 = fmaf(a2.y, v1[9], s1);
    s1 = fmaf(a2.z, v1[10], s1); s1 = fmaf(a2.w, v1[11], s1);
    s1 = fmaf(a3.x, v1[12], s1); s1 = fmaf(a3.y, v1[13], s1);
    s1 = fmaf(a3.z, v1[14], s1); s1 = fmaf(a3.w, v1[15], s1);
    s2 = fmaf(a0.x, v2[0], s2);  s2 = fmaf(a0.y, v2[1], s2);
    s2 = fmaf(a0.z, v2[2], s2);  s2 = fmaf(a0.w, v2[3], s2);
    s2 = fmaf(a1.x, v2[4], s2);  s2 = fmaf(a1.y, v2[5], s2);
    s2 = fmaf(a1.z, v2[6], s2);  s2 = fmaf(a1.w, v2[7], s2);
    s2 = fmaf(a2.x, v2[8], s2);  s2 = fmaf(a2.y, v2[9], s2);
    s2 = fmaf(a2.z, v2[10], s2); s2 = fmaf(a2.w, v2[11], s2);
    s2 = fmaf(a3.x, v2[12], s2); s2 = fmaf(a3.y, v2[13], s2);
    s2 = fmaf(a3.z, v2[14], s2); s2 = fmaf(a3.w, v2[15], s2);
    int p = atomicAdd(&cursor[d], 1);
    recs[offs[d] + p] = make_int4(s, e, __float_as_int(s1), __float_as_int(s2));
}

#define FMA4(o_, s_, w_)                                                 \
    o_.x = fmaf(s_, w_.x, o_.x); o_.y = fmaf(s_, w_.y, o_.y);            \
    o_.z = fmaf(s_, w_.z, o_.z); o_.w = fmaf(s_, w_.w, o_.w);

// xp = x @ w_n ; sa = xp@qa ; sb = xp@ka.
// lane = (batch, cout/4): each lane accumulates a float4 of outputs; x row and
// w_n read straight from L1/L2 as broadcast float4s -> zero LDS traffic.
__global__ __launch_bounds__(256) void node_prep_kernel(
    const float* __restrict__ x, const float* __restrict__ w_n,
    const float* __restrict__ qa, const float* __restrict__ ka,
    float* __restrict__ xp, float* __restrict__ sa, float* __restrict__ sb) {
    int t = threadIdx.x, wave = t >> 6, lane = t & 63;
    int node = blockIdx.x * 4 + wave;
    int b = lane >> 4, q4 = (lane & 15) << 2;
    const float* xrow = x + (size_t)node * (BB * CC) + b * CC;
    const float* wq = w_n + q4;
    float4 acc = make_float4(0.f, 0.f, 0.f, 0.f);
    #pragma unroll 4
    for (int c4 = 0; c4 < 16; ++c4) {
        float4 xv = *(const float4*)(xrow + 4 * c4);
        const float* wp = wq + (size_t)(4 * c4) * CC;
        float4 w0 = *(const float4*)(wp);
        float4 w1 = *(const float4*)(wp + CC);
        float4 w2 = *(const float4*)(wp + 2 * CC);
        float4 w3 = *(const float4*)(wp + 3 * CC);
        FMA4(acc, xv.x, w0); FMA4(acc, xv.y, w1);
        FMA4(acc, xv.z, w2); FMA4(acc, xv.w, w3);
    }
    *(float4*)(xp + (size_t)node * (BB * CC) + b * CC + q4) = acc;
    float4 qv = *(const float4*)(qa + q4);
    float4 kv = *(const float4*)(ka + q4);
    float ra = acc.x * qv.x + acc.y * qv.y + acc.z * qv.z + acc.w * qv.w;
    float rb = acc.x * kv.x + acc.y * kv.y + acc.z * kv.z + acc.w * kv.w;
    #pragma unroll
    for (int off = 1; off < 16; off <<= 1) {   // reduce within 16-lane q-group
        ra += __shfl_xor(ra, off, 64);
        rb += __shfl_xor(rb, off, 64);
    }
    if ((lane & 15) == 0) {
        sa[node * BB + b] = ra;
        sb[node * BB + b] = rb;
    }
}

// ---- fused attention + segment-max + output linear + residual + leaky_relu ----
// Edge loop: lane = channel; depth-2 pipelined (recs 2 ahead, {attr,sa,xp} 1 ahead
// in 2 rotating register slots). Epilogue: lane = (batch, cout/4); LDS only for
// the aggr redistribution (pad 68 -> conflict-free b128 broadcasts).
#define LOADS(R_, P) {                                                        \
    const float4* ap_ = (const float4*)(attr + (size_t)(R_).y * CE);          \
    P##a0 = ap_[0]; P##a1 = ap_[1]; P##a2 = ap_[2]; P##a3 = ap_[3];           \
    P##sa = *(const float4*)(sag + (size_t)(R_).x * BB);                      \
    const float* xr_ = xp + (size_t)(R_).x * (BB * CC) + lane;                \
    P##x0 = xr_[0]; P##x1 = xr_[CC]; P##x2 = xr_[2 * CC]; P##x3 = xr_[3 * CC]; }

#define COMPUTE(R_, P) {                                                      \
    float g_ = 0.f;                                                           \
    g_ = fmaf(P##a0.x, wec[0], g_);  g_ = fmaf(P##a0.y, wec[1], g_);          \
    g_ = fmaf(P##a0.z, wec[2], g_);  g_ = fmaf(P##a0.w, wec[3], g_);          \
    g_ = fmaf(P##a1.x, wec[4], g_);  g_ = fmaf(P##a1.y, wec[5], g_);          \
    g_ = fmaf(P##a1.z, wec[6], g_);  g_ = fmaf(P##a1.w, wec[7], g_);          \
    g_ = fmaf(P##a2.x, wec[8], g_);  g_ = fmaf(P##a2.y, wec[9], g_);          \
    g_ = fmaf(P##a2.z, wec[10], g_); g_ = fmaf(P##a2.w, wec[11], g_);         \
    g_ = fmaf(P##a3.x, wec[12], g_); g_ = fmaf(P##a3.y, wec[13], g_);         \
    g_ = fmaf(P##a3.z, wec[14], g_); g_ = fmaf(P##a3.w, wec[15], g_);         \
    g_ = sigmoidf_(g_);                                                       \
    float se_ = __int_as_float(sel ? (R_).w : (R_).z);                        \
    float t0_ = sigmoidf_(P##sa.x + sb4.x + se_);                             \
    float t1_ = sigmoidf_(P##sa.y + sb4.y + se_);                             \
    float t2_ = sigmoidf_(P##sa.z + sb4.z + se_);                             \
    float t3_ = sigmoidf_(P##sa.w + sb4.w + se_);                             \
    m0 = fmaxf(m0, t0_ * P##x0 * g_);                                         \
    m1 = fmaxf(m1, t1_ * P##x1 * g_);                                         \
    m2 = fmaxf(m2, t2_ * P##x2 * g_);                                         \
    m3 = fmaxf(m3, t3_ * P##x3 * g_); }

__global__ __launch_bounds__(256) void conv_out_kernel(
    const float* __restrict__ xp,      // [NN,BB,CC]
    const int4* __restrict__ recs,     // [EE] {src, e, se1, se2}
    const int* __restrict__ offs,      // [NN+1]
    const float* __restrict__ attr,    // [EE,CE]
    const float* __restrict__ w_e,     // [CE,CC]
    const float* __restrict__ ow,      // [2*CC,CC]
    const float* __restrict__ ob,      // [CC]
    const float* __restrict__ sag,     // [NN,BB]
    const float* __restrict__ sbg,     // [NN,BB]
    float* __restrict__ out,           // [NN,BB,CC]
    int sel) {
    __shared__ float aggr_sh[4][BB * 68];  // pad 68: conflict-free (b,q) b128 reads
    int t = threadIdx.x, wave = t >> 6, lane = t & 63;
    int node = blockIdx.x * 4 + wave;
    float wec[CE];
    #pragma unroll
    for (int j = 0; j < CE; ++j) wec[j] = w_e[j * CC + lane];
    float4 sb4 = *(const float4*)(sbg + (size_t)node * BB);
    int o0 = offs[node], o1 = offs[node + 1];
    int n = o1 - o0;
    const int4* rp = recs + o0;
    float m0 = -INFINITY, m1 = -INFINITY, m2 = -INFINITY, m3 = -INFINITY;
    float4 Aa0, Aa1, Aa2, Aa3, Asa; float Ax0, Ax1, Ax2, Ax3;
    float4 Ba0, Ba1, Ba2, Ba3, Bsa; float Bx0, Bx1, Bx2, Bx3;
    int4 rA = make_int4(0, 0, 0, 0), rB = rA;
    if (n > 0) { rA = rp[0]; LOADS(rA, A); }
    if (n > 1) { rB = rp[1]; LOADS(rB, B); }
    int i = 0;
    #pragma unroll 1
    for (; i + 2 < n; i += 2) {
        int4 rA2 = rp[i + 2];
        int4 rB2 = (i + 3 < n) ? rp[i + 3] : rA2;
        COMPUTE(rA, A);
        LOADS(rA2, A);
        COMPUTE(rB, B);
        LOADS(rB2, B);
        rA = rA2; rB = rB2;
    }
    if (i < n)     COMPUTE(rA, A);
    if (i + 1 < n) COMPUTE(rB, B);
    // empty segments -> 0
    m0 = (m0 == -INFINITY) ? 0.f : m0;
    m1 = (m1 == -INFINITY) ? 0.f : m1;
    m2 = (m2 == -INFINITY) ? 0.f : m2;
    m3 = (m3 == -INFINITY) ? 0.f : m3;

    float* ash = aggr_sh[wave];        // wave-private region: no __syncthreads needed
    ash[0 * 68 + lane] = m0;
    ash[1 * 68 + lane] = m1;
    ash[2 * 68 + lane] = m2;
    ash[3 * 68 + lane] = m3;
    asm volatile("s_waitcnt lgkmcnt(0)" ::: "memory");  // in-wave LDS RAW fence

    int b = lane >> 4, q4 = (lane & 15) << 2;
    const float* agr = ash + b * 68;
    const float* xrow = xp + (size_t)node * (BB * CC) + b * CC;
    const float* owa = ow + q4;
    const float* owb = ow + CC * CC + q4;
    float4 o = make_float4(0.f, 0.f, 0.f, 0.f);
    #pragma unroll 2
    for (int c4 = 0; c4 < 16; ++c4) {
        float4 xv = *(const float4*)(xrow + 4 * c4);   // global broadcast (L1/L2)
        float4 av = *(const float4*)(agr + 4 * c4);    // 1 ds_read_b128, conflict-free
        const float* wpa = owa + (size_t)(4 * c4) * CC;
        float4 w0 = *(const float4*)(wpa);
        float4 w1 = *(const float4*)(wpa + CC);
        float4 w2 = *(const float4*)(wpa + 2 * CC);
        float4 w3 = *(const float4*)(wpa + 3 * CC);
        const float* wpb = owb + (size_t)(4 * c4) * CC;
        float4 u0 = *(const float4*)(wpb);
        float4 u1 = *(const float4*)(wpb + CC);
        float4 u2 = *(const float4*)(wpb + 2 * CC);
        float4 u3 = *(const float4*)(wpb + 3 * CC);
        FMA4(o, xv.x, w0); FMA4(o, xv.y, w1); FMA4(o, xv.z, w2); FMA4(o, xv.w, w3);
        FMA4(o, av.x, u0); FMA4(o, av.y, u1); FMA4(o, av.z, u2); FMA4(o, av.w, u3);
    }
    float4 xnv = *(const float4*)(xrow + q4);
    float4 ob4 = *(const float4*)(ob + q4);
    float4 r;
    r.x = xnv.x + o.x + ob4.x;
    r.y = xnv.y + o.y + ob4.y;
    r.z = xnv.z + o.z + ob4.z;
    r.w = xnv.w + o.w + ob4.w;
    r.x = (r.x > 0.f) ? r.x : 0.01f * r.x;
    r.y = (r.y > 0.f) ? r.y : 0.01f * r.y;
    r.z = (r.z > 0.f) ? r.z : 0.01f * r.z;
    r.w = (r.w > 0.f) ? r.w : 0.01f * r.w;
    *(float4*)(out + (size_t)node * (BB * CC) + b * CC + q4) = r;
}

extern "C" void kernel_launch(void* const* d_in, const int* in_sizes, int n_in,
                              void* d_out, int out_size, void* d_ws, size_t ws_size,
                              hipStream_t stream) {
    const float* X    = (const float*)d_in[0];
    const int*   ei   = (const int*)d_in[1];
    const float* attr = (const float*)d_in[2];
    const float* w_n1 = (const float*)d_in[3];
    const float* w_e1 = (const float*)d_in[4];
    const float* q1   = (const float*)d_in[5];
    const float* k1   = (const float*)d_in[6];
    const float* aw1  = (const float*)d_in[7];
    const float* ab1  = (const float*)d_in[8];
    const float* ow1  = (const float*)d_in[9];
    const float* ob1  = (const float*)d_in[10];
    const float* w_n2 = (const float*)d_in[11];
    const float* w_e2 = (const float*)d_in[12];
    const float* q2   = (const float*)d_in[13];
    const float* k2   = (const float*)d_in[14];
    const float* aw2  = (const float*)d_in[15];
    const float* ab2  = (const float*)d_in[16];
    const float* ow2  = (const float*)d_in[17];
    const float* ob2  = (const float*)d_in[18];
    float* out = (float*)d_out;

    char* ws = (char*)d_ws;
    float* xpA    = (float*)(ws + OFF_XPA);
    float* xpB    = (float*)(ws + OFF_XPB);
    float* sa     = (float*)(ws + OFF_SA);
    float* sb     = (float*)(ws + OFF_SB);
    float* vecs   = (float*)(ws + OFF_VECS);
    int*   counts = (int*)(ws + OFF_COUNTS);
    int*   cursor = (int*)(ws + OFF_CURSOR);
    int*   offs   = (int*)(ws + OFF_OFFS);
    int4*  recs   = (int4*)(ws + OFF_RECS);

    // CSR build (edge_index is layer-invariant)
    hipMemsetAsync(counts, 0, 2 * NN * sizeof(int), stream);  // counts + cursor
    hist_vecs_kernel<<<EE / 256, 256, 0, stream>>>(ei, counts, q1, k1, aw1, w_e1,
                                                   q2, k2, aw2, w_e2, vecs);
    scan_kernel<<<1, 1024, 0, stream>>>(counts, offs, NN);
    scatter_kernel<<<EE / 256, 256, 0, stream>>>(ei, offs, cursor, attr, vecs,
                                                 ab1, ab2, recs);
    // layer 1
    node_prep_kernel<<<NN / 4, 256, 0, stream>>>(X, w_n1, vecs + 0, vecs + 64, xpA, sa, sb);
    conv_out_kernel<<<NN / 4, 256, 0, stream>>>(xpA, recs, offs, attr, w_e1,
                                                ow1, ob1, sa, sb, xpB, 0);
    // layer 2
    node_prep_kernel<<<NN / 4, 256, 0, stream>>>(xpB, w_n2, vecs + 144, vecs + 208, xpA, sa, sb);
    conv_out_kernel<<<NN / 4, 256, 0, stream>>>(xpA, recs, offs, attr, w_e2,
                                                ow2, ob2, sa, sb, out, 1);
}

// Round 2
// 289.635 us; speedup vs baseline: 1.2192x; 1.2192x over previous
//
#include <hip/hip_runtime.h>
#include <math.h>

#define NN 10000
#define BB 4
#define EE 160000
#define CC 64
#define CE 16

// ---- workspace layout (bytes) ----
static constexpr size_t OFF_XPA    = 0;          // float[NN*BB*CC]
static constexpr size_t OFF_XPB    = 10240000;   // float[NN*BB*CC]
static constexpr size_t OFF_SA     = 20480000;   // float[NN*BB]
static constexpr size_t OFF_SB     = 20640000;   // float[NN*BB]
static constexpr size_t OFF_VECS   = 20800000;   // float[288]
static constexpr size_t OFF_COUNTS = 20801280;   // int[NN]
static constexpr size_t OFF_CURSOR = 20841280;   // int[NN]
static constexpr size_t OFF_OFFS   = 20881280;   // int[NN+1]
static constexpr size_t OFF_RECS   = 20921344;   // int2[EE]   (1.28 MB)
static constexpr size_t OFF_ATT    = 22201344;   // float4[EE] (2.56 MB)
static constexpr size_t OFF_SE12   = 24761344;   // float2[EE] (1.28 MB)
static constexpr size_t OFF_ORDER  = 26041344;   // int[NN]    -> total ~26.1 MB

__device__ __forceinline__ float sigmoidf_(float x) {
    // v_rcp_f32 (~1ulp) instead of IEEE divide; validated absmax-identical in r1
    return __builtin_amdgcn_rcpf(1.0f + __expf(-x));
}

// histogram of dst + (block 0) fold q@aw_q, k@aw_k, w_e@aw_e for both layers
__global__ void hist_vecs_kernel(const int* __restrict__ ei, int* __restrict__ counts,
                                 const float* __restrict__ q1, const float* __restrict__ k1,
                                 const float* __restrict__ aw1, const float* __restrict__ we1,
                                 const float* __restrict__ q2, const float* __restrict__ k2,
                                 const float* __restrict__ aw2, const float* __restrict__ we2,
                                 float* __restrict__ vecs) {
    int e = blockIdx.x * blockDim.x + threadIdx.x;
    if (e < EE) atomicAdd(&counts[ei[EE + e]], 1);
    if (blockIdx.x == 0) {
        int t = threadIdx.x;
        if (t < 64) {
            float a = 0.f, b = 0.f, c = 0.f, d = 0.f;
            for (int j = 0; j < 64; ++j) {
                a = fmaf(q1[t * 64 + j], aw1[j], a);
                b = fmaf(k1[t * 64 + j], aw1[64 + j], b);
                c = fmaf(q2[t * 64 + j], aw2[j], c);
                d = fmaf(k2[t * 64 + j], aw2[64 + j], d);
            }
            vecs[t] = a; vecs[64 + t] = b; vecs[144 + t] = c; vecs[208 + t] = d;
        }
        if (t < 16) {
            float a = 0.f, b = 0.f;
            for (int j = 0; j < 64; ++j) {
                a = fmaf(we1[t * 64 + j], aw1[128 + j], a);
                b = fmaf(we2[t * 64 + j], aw2[128 + j], b);
            }
            vecs[128 + t] = a; vecs[272 + t] = b;
        }
    }
}

// single-block exclusive scan of counts[0..n) -> offs[0..n].  1 barrier.
__global__ __launch_bounds__(1024) void scan_kernel(const int* __restrict__ counts,
                                                    int* __restrict__ offs, int n) {
    __shared__ int wsum[16];
    int t = threadIdx.x;
    int base = t * 10;
    int v[10];
    int s = 0;
    #pragma unroll
    for (int j = 0; j < 10; ++j) {
        int i = base + j;
        v[j] = (i < n) ? counts[i] : 0;
        s += v[j];
    }
    int lane = t & 63, wid = t >> 6;
    int ps = s;
    #pragma unroll
    for (int off = 1; off < 64; off <<= 1) {
        int u = __shfl_up(ps, off, 64);
        if (lane >= off) ps += u;
    }
    if (lane == 63) wsum[wid] = ps;
    __syncthreads();
    int wbase = 0;
    for (int w = 0; w < wid; ++w) wbase += wsum[w];
    int tb = wbase + ps - s;  // exclusive prefix for this thread
    #pragma unroll
    for (int j = 0; j < 10; ++j) {
        int i = base + j;
        if (i < n) offs[i] = tb;
        tb += v[j];
    }
    if (t == 1023) offs[n] = tb;
}

// counting-sort nodes by degree DESCENDING -> order[].  Single block.
// LPT scheduling for conv_out: heavy blocks first + equal degrees within a block.
__global__ __launch_bounds__(1024) void order_kernel(const int* __restrict__ counts,
                                                     int* __restrict__ order) {
    __shared__ int hist[1024];
    __shared__ int startb[1024];
    __shared__ int cur[1024];
    __shared__ int wsum[16];
    int t = threadIdx.x;
    hist[t] = 0; cur[t] = 0;
    __syncthreads();
    int dg[10];
    #pragma unroll
    for (int j = 0; j < 10; ++j) {
        int i = t * 10 + j;
        dg[j] = -1;
        if (i < NN) {
            int d = counts[i];
            d = (d > 1023) ? 1023 : d;
            dg[j] = d;
            atomicAdd(&hist[d], 1);
        }
    }
    __syncthreads();
    // suffix sums: startb[r] = #nodes with degree > r  (scan bins in descending order)
    int r = 1023 - t;
    int v = hist[r];
    int lane = t & 63, wid = t >> 6;
    int ps = v;
    #pragma unroll
    for (int off = 1; off < 64; off <<= 1) {
        int u = __shfl_up(ps, off, 64);
        if (lane >= off) ps += u;
    }
    if (lane == 63) wsum[wid] = ps;
    __syncthreads();
    int wbase = 0;
    for (int w = 0; w < wid; ++w) wbase += wsum[w];
    startb[r] = wbase + ps - v;
    __syncthreads();
    #pragma unroll
    for (int j = 0; j < 10; ++j) {
        if (dg[j] >= 0) {
            int pos = startb[dg[j]] + atomicAdd(&cur[dg[j]], 1);
            order[pos] = t * 10 + j;
        }
    }
}

// CSR scatter; also fold attr·(w_e@aw_e)+ab per edge for both layers -> se12[e]
// (so att_kernel never touches the 10 MB attr array).
__global__ __launch_bounds__(256) void scatter_kernel(
    const int* __restrict__ ei, const int* __restrict__ offs,
    int* __restrict__ cursor, const float* __restrict__ attr,
    const float* __restrict__ vecs, const float* __restrict__ ab1,
    const float* __restrict__ ab2, int2* __restrict__ recs,
    float2* __restrict__ se12) {
    int e = blockIdx.x * blockDim.x + threadIdx.x;
    if (e >= EE) return;
    int s = ei[e], d = ei[EE + e];
    const float4* ap = (const float4*)(attr + (size_t)e * CE);
    float4 a0 = ap[0], a1 = ap[1], a2 = ap[2], a3 = ap[3];
    const float* v1 = vecs + 128;
    const float* v2 = vecs + 272;
    float s1 = ab1[0], s2 = ab2[0];
    s1 = fmaf(a0.x, v1[0], s1);  s1 = fmaf(a0.y, v1[1], s1);
    s1 = fmaf(a0.z, v1[2], s1);  s1 = fmaf(a0.w, v1[3], s1);
    s1 = fmaf(a1.x, v1[4], s1);  s1 = fmaf(a1.y, v1[5], s1);
    s1 = fmaf(a1.z, v1[6], s1);  s1 = fmaf(a1.w, v1[7], s1);
    s1 = fmaf(a2.x, v1[8], s1);  s1 = fmaf(a2.y, v1[9], s1);
    s1 = fmaf(a2.z, v1[10], s1); s1 = fmaf(a2.w, v1[11], s1);
    s1 = fmaf(a3.x, v1[12], s1); s1 = fmaf(a3.y, v1[13], s1);
    s1 = fmaf(a3.z, v1[14], s1); s1 = fmaf(a3.w, v1[15], s1);
    s2 = fmaf(a0.x, v2[0], s2);  s2 = fmaf(a0.y, v2[1], s2);
    s2 = fmaf(a0.z, v2[2], s2);  s2 = fmaf(a0.w, v2[3], s2);
    s2 = fmaf(a1.x, v2[4], s2);  s2 = fmaf(a1.y, v2[5], s2);
    s2 = fmaf(a1.z, v2[6], s2);  s2 = fmaf(a1.w, v2[7], s2);
    s2 = fmaf(a2.x, v2[8], s2);  s2 = fmaf(a2.y, v2[9], s2);
    s2 = fmaf(a2.z, v2[10], s2); s2 = fmaf(a2.w, v2[11], s2);
    s2 = fmaf(a3.x, v2[12], s2); s2 = fmaf(a3.y, v2[13], s2);
    s2 = fmaf(a3.z, v2[14], s2); s2 = fmaf(a3.w, v2[15], s2);
    int p = atomicAdd(&cursor[d], 1);
    recs[offs[d] + p] = make_int2(s, e);
    se12[e] = make_float2(s1, s2);
}

// xp = x @ w_n ; sa = xp@qa ; sb = xp@ka.  One wave per node, 4 nodes/block.
// (round-0 proven version)
__global__ __launch_bounds__(256) void node_prep_kernel(
    const float* __restrict__ x,   // [NN,BB,CC]
    const float* __restrict__ w_n, // [CC,CC]
    const float* __restrict__ qa,  // [64]
    const float* __restrict__ ka,  // [64]
    float* __restrict__ xp,        // [NN,BB,CC]
    float* __restrict__ sa,
    float* __restrict__ sb) {
    __shared__ float w_sh[64 * 64];     // 16 KB
    __shared__ float x_sh[4 * BB * CC]; // 4 KB
    int t = threadIdx.x;
    for (int i = t; i < 64 * 64; i += 256) w_sh[i] = w_n[i];
    int node0 = blockIdx.x * 4;
    const float4* xg = (const float4*)(x + (size_t)node0 * BB * CC);
    ((float4*)x_sh)[t] = xg[t];
    __syncthreads();
    int wave = t >> 6, lane = t & 63;
    int node = node0 + wave;
    const float* xrow = x_sh + wave * BB * CC;
    float acc0 = 0.f, acc1 = 0.f, acc2 = 0.f, acc3 = 0.f;
    #pragma unroll 8
    for (int ci = 0; ci < 64; ++ci) {
        float w = w_sh[ci * 64 + lane];
        acc0 = fmaf(xrow[ci], w, acc0);
        acc1 = fmaf(xrow[64 + ci], w, acc1);
        acc2 = fmaf(xrow[128 + ci], w, acc2);
        acc3 = fmaf(xrow[192 + ci], w, acc3);
    }
    size_t obase = (size_t)node * BB * CC + lane;
    xp[obase] = acc0;
    xp[obase + 64] = acc1;
    xp[obase + 128] = acc2;
    xp[obase + 192] = acc3;
    float qv = qa[lane], kv = ka[lane];
    float ra0 = acc0 * qv, ra1 = acc1 * qv, ra2 = acc2 * qv, ra3 = acc3 * qv;
    float rb0 = acc0 * kv, rb1 = acc1 * kv, rb2 = acc2 * kv, rb3 = acc3 * kv;
    #pragma unroll
    for (int off = 32; off >= 1; off >>= 1) {
        ra0 += __shfl_xor(ra0, off, 64); ra1 += __shfl_xor(ra1, off, 64);
        ra2 += __shfl_xor(ra2, off, 64); ra3 += __shfl_xor(ra3, off, 64);
        rb0 += __shfl_xor(rb0, off, 64); rb1 += __shfl_xor(rb1, off, 64);
        rb2 += __shfl_xor(rb2, off, 64); rb3 += __shfl_xor(rb3, off, 64);
    }
    if (lane == 0) {
        sa[node * BB + 0] = ra0; sa[node * BB + 1] = ra1;
        sa[node * BB + 2] = ra2; sa[node * BB + 3] = ra3;
        sb[node * BB + 0] = rb0; sb[node * BB + 1] = rb1;
        sb[node * BB + 2] = rb2; sb[node * BB + 3] = rb3;
    }
}

// per-edge attention scalar: att4[e] = sigmoid(sa[src] + sb[dst] + se12[e])
// slim: no attr read (se12 precomputed in scatter). ~6 MB traffic per call.
__global__ __launch_bounds__(256) void att_kernel(
    const int* __restrict__ ei, const float2* __restrict__ se12,
    const float* __restrict__ sa, const float* __restrict__ sb,
    float4* __restrict__ att, int sel) {
    int e = blockIdx.x * blockDim.x + threadIdx.x;
    if (e >= EE) return;
    int s = ei[e], d = ei[EE + e];
    float2 se2 = se12[e];
    float se = sel ? se2.y : se2.x;
    float4 sas = *(const float4*)(sa + (size_t)s * BB);
    float4 sbn = *(const float4*)(sb + (size_t)d * BB);
    float4 r;
    r.x = sigmoidf_(sas.x + sbn.x + se);
    r.y = sigmoidf_(sas.y + sbn.y + se);
    r.z = sigmoidf_(sas.z + sbn.z + se);
    r.w = sigmoidf_(sas.w + sbn.w + se);
    att[e] = r;
}

// Per-node segment-max aggregation + output linear + residual + leaky_relu.
// One wave per node (lane = channel), 4 nodes per block.  round-0 proven body,
// plus: (a) nodes taken in degree-descending order (LPT), (b) no __syncthreads
// (LDS regions are wave-private; in-wave lgkmcnt fence suffices).
__global__ __launch_bounds__(256) void conv_out_kernel(
    const float* __restrict__ xp,      // [NN,BB,CC]
    const int2* __restrict__ recs,     // [EE] {src, e}
    const int* __restrict__ offs,      // [NN+1]
    const float* __restrict__ attr,    // [EE,CE]
    const float* __restrict__ w_e,     // [CE,CC]
    const float4* __restrict__ att,    // [EE]
    const float* __restrict__ ow,      // [2*CC,CC]
    const float* __restrict__ ob,      // [CC]
    const int* __restrict__ order,     // [NN] degree-descending node ids
    float* __restrict__ out) {         // [NN,BB,CC]
    __shared__ float aggr_sh[4][BB * CC];  // 4 KB (wave-private rows)
    __shared__ float xpn_sh[4][BB * CC];   // 4 KB
    int t = threadIdx.x;
    int wave = t >> 6, lane = t & 63;
    int node = order[blockIdx.x * 4 + wave];

    float wec[CE];
    #pragma unroll
    for (int j = 0; j < CE; ++j) wec[j] = w_e[j * CC + lane];

    const float* xn = xp + (size_t)node * BB * CC + lane;
    float xn0 = xn[0], xn1 = xn[64], xn2 = xn[128], xn3 = xn[192];

    int o0 = offs[node], o1 = offs[node + 1];
    float m0 = -INFINITY, m1 = -INFINITY, m2 = -INFINITY, m3 = -INFINITY;

    int i = o0;
    int2 rec = (i < o1) ? recs[i] : make_int2(0, 0);
    while (i < o1) {
        int2 cur = rec;
        ++i;
        if (i < o1) rec = recs[i];  // prefetch next
        int s = cur.x, e = cur.y;
        float4 at = att[e];
        const float4* ap = (const float4*)(attr + (size_t)e * CE);
        float4 a0 = ap[0], a1 = ap[1], a2 = ap[2], a3 = ap[3];
        float g = 0.f;
        g = fmaf(a0.x, wec[0], g);  g = fmaf(a0.y, wec[1], g);
        g = fmaf(a0.z, wec[2], g);  g = fmaf(a0.w, wec[3], g);
        g = fmaf(a1.x, wec[4], g);  g = fmaf(a1.y, wec[5], g);
        g = fmaf(a1.z, wec[6], g);  g = fmaf(a1.w, wec[7], g);
        g = fmaf(a2.x, wec[8], g);  g = fmaf(a2.y, wec[9], g);
        g = fmaf(a2.z, wec[10], g); g = fmaf(a2.w, wec[11], g);
        g = fmaf(a3.x, wec[12], g); g = fmaf(a3.y, wec[13], g);
        g = fmaf(a3.z, wec[14], g); g = fmaf(a3.w, wec[15], g);
        g = sigmoidf_(g);
        const float* xs = xp + (size_t)s * BB * CC + lane;
        float x0 = xs[0], x1 = xs[64], x2 = xs[128], x3 = xs[192];
        m0 = fmaxf(m0, at.x * x0 * g);
        m1 = fmaxf(m1, at.y * x1 * g);
        m2 = fmaxf(m2, at.z * x2 * g);
        m3 = fmaxf(m3, at.w * x3 * g);
    }
    // empty segments -> 0
    m0 = (m0 == -INFINITY) ? 0.f : m0;
    m1 = (m1 == -INFINITY) ? 0.f : m1;
    m2 = (m2 == -INFINITY) ? 0.f : m2;
    m3 = (m3 == -INFINITY) ? 0.f : m3;

    aggr_sh[wave][0 * CC + lane] = m0; aggr_sh[wave][1 * CC + lane] = m1;
    aggr_sh[wave][2 * CC + lane] = m2; aggr_sh[wave][3 * CC + lane] = m3;
    xpn_sh[wave][0 * CC + lane] = xn0; xpn_sh[wave][1 * CC + lane] = xn1;
    xpn_sh[wave][2 * CC + lane] = xn2; xpn_sh[wave][3 * CC + lane] = xn3;
    asm volatile("s_waitcnt lgkmcnt(0)" ::: "memory");  // in-wave LDS RAW fence

    const float* xr = xpn_sh[wave];
    const float* ar = aggr_sh[wave];
    float o0f = 0.f, o1f = 0.f, o2f = 0.f, o3f = 0.f;
    #pragma unroll 4
    for (int ci = 0; ci < 64; ++ci) {
        float wa = ow[ci * 64 + lane];         // L2-resident, same 32 KB per block
        float wb = ow[(64 + ci) * 64 + lane];
        o0f = fmaf(xr[ci], wa, o0f);
        o1f = fmaf(xr[CC + ci], wa, o1f);
        o2f = fmaf(xr[2 * CC + ci], wa, o2f);
        o3f = fmaf(xr[3 * CC + ci], wa, o3f);
        o0f = fmaf(ar[ci], wb, o0f);
        o1f = fmaf(ar[CC + ci], wb, o1f);
        o2f = fmaf(ar[2 * CC + ci], wb, o2f);
        o3f = fmaf(ar[3 * CC + ci], wb, o3f);
    }
    // out = xp + (concat([xp, aggr]) @ ow + ob), then leaky_relu(0.01)
    float obv = ob[lane];
    float r0 = xn0 + o0f + obv;
    float r1 = xn1 + o1f + obv;
    float r2 = xn2 + o2f + obv;
    float r3 = xn3 + o3f + obv;
    r0 = (r0 > 0.f) ? r0 : 0.01f * r0;
    r1 = (r1 > 0.f) ? r1 : 0.01f * r1;
    r2 = (r2 > 0.f) ? r2 : 0.01f * r2;
    r3 = (r3 > 0.f) ? r3 : 0.01f * r3;
    float* op = out + (size_t)node * BB * CC + lane;
    op[0] = r0; op[64] = r1; op[128] = r2; op[192] = r3;
}

extern "C" void kernel_launch(void* const* d_in, const int* in_sizes, int n_in,
                              void* d_out, int out_size, void* d_ws, size_t ws_size,
                              hipStream_t stream) {
    const float* X    = (const float*)d_in[0];
    const int*   ei   = (const int*)d_in[1];
    const float* attr = (const float*)d_in[2];
    const float* w_n1 = (const float*)d_in[3];
    const float* w_e1 = (const float*)d_in[4];
    const float* q1   = (const float*)d_in[5];
    const float* k1   = (const float*)d_in[6];
    const float* aw1  = (const float*)d_in[7];
    const float* ab1  = (const float*)d_in[8];
    const float* ow1  = (const float*)d_in[9];
    const float* ob1  = (const float*)d_in[10];
    const float* w_n2 = (const float*)d_in[11];
    const float* w_e2 = (const float*)d_in[12];
    const float* q2   = (const float*)d_in[13];
    const float* k2   = (const float*)d_in[14];
    const float* aw2  = (const float*)d_in[15];
    const float* ab2  = (const float*)d_in[16];
    const float* ow2  = (const float*)d_in[17];
    const float* ob2  = (const float*)d_in[18];
    float* out = (float*)d_out;

    char* ws = (char*)d_ws;
    float*  xpA    = (float*)(ws + OFF_XPA);
    float*  xpB    = (float*)(ws + OFF_XPB);
    float*  sa     = (float*)(ws + OFF_SA);
    float*  sb     = (float*)(ws + OFF_SB);
    float*  vecs   = (float*)(ws + OFF_VECS);
    int*    counts = (int*)(ws + OFF_COUNTS);
    int*    cursor = (int*)(ws + OFF_CURSOR);
    int*    offs   = (int*)(ws + OFF_OFFS);
    int2*   recs   = (int2*)(ws + OFF_RECS);
    float4* att    = (float4*)(ws + OFF_ATT);
    float2* se12   = (float2*)(ws + OFF_SE12);
    int*    order  = (int*)(ws + OFF_ORDER);

    // CSR build (edge_index is layer-invariant)
    hipMemsetAsync(counts, 0, 2 * NN * sizeof(int), stream);  // counts + cursor
    hist_vecs_kernel<<<EE / 256, 256, 0, stream>>>(ei, counts, q1, k1, aw1, w_e1,
                                                   q2, k2, aw2, w_e2, vecs);
    scan_kernel<<<1, 1024, 0, stream>>>(counts, offs, NN);
    order_kernel<<<1, 1024, 0, stream>>>(counts, order);
    scatter_kernel<<<EE / 256, 256, 0, stream>>>(ei, offs, cursor, attr, vecs,
                                                 ab1, ab2, recs, se12);
    // layer 1
    node_prep_kernel<<<NN / 4, 256, 0, stream>>>(X, w_n1, vecs + 0, vecs + 64, xpA, sa, sb);
    att_kernel<<<EE / 256, 256, 0, stream>>>(ei, se12, sa, sb, att, 0);
    conv_out_kernel<<<NN / 4, 256, 0, stream>>>(xpA, recs, offs, attr, w_e1, att,
                                                ow1, ob1, order, xpB);
    // layer 2
    node_prep_kernel<<<NN / 4, 256, 0, stream>>>(xpB, w_n2, vecs + 144, vecs + 208, xpA, sa, sb);
    att_kernel<<<EE / 256, 256, 0, stream>>>(ei, se12, sa, sb, att, 1);
    conv_out_kernel<<<NN / 4, 256, 0, stream>>>(xpA, recs, offs, attr, w_e2, att,
                                                ow2, ob2, order, out);
}